// Round 2
// 649.282 us; speedup vs baseline: 1.0002x; 1.0002x over previous
//
#include <hip/hip_runtime.h>

// QLORA: Y = X @ (W_nf4*c1*c2) + (X @ L1) @ L2
// M=8192, K=4096, N=4096, RANK=16.
// R5 changes vs R3 (R4's hand-rolled 8-phase GEMM failed correctness; reverted):
//  - LoRA is NO LONGER folded into W during prep. prep-W is now pure
//    streaming dequant+transpose (column-coalesced reads, no LDS, no rank-16
//    loop) -- removes the DS-pipe-bound inner loop that made prep ~5x its
//    memory roofline.
//  - New tiny kernel xl1_kernel: T = Xh @ L1 via one 16x16x32 MFMA chain per
//    16-row tile (B-operand from pre-transposed bf16 L1t).
//  - GEMM epilogue adds the LoRA term with one K=16 MFMA step per wave
//    (A = T rows cast to bf16, B = L2t rows), accumulating into acc before
//    the C-store. GEMM main loop is exactly R3's verified structure.
//  - Small arrays (Tg fp32, L1t/L2t bf16) are __device__ globals; workspace
//    layout (Xh 64MB + Wt 32MB) unchanged.

#define M_ROWS 8192
#define K_DIM  4096
#define N_OUT  4096
#define CVT_BLOCKS 16384        // M*K/8/256
#define WP_BLOCKS  8192         // (N/64)*(K/32)
#define TR_BLOCKS  32           // (4096 + 4096) threads / 256

typedef float  f32x16 __attribute__((ext_vector_type(16)));
typedef __bf16 bf16x8 __attribute__((ext_vector_type(8)));
typedef float  f32x4  __attribute__((ext_vector_type(4)));
typedef unsigned short ushort8v __attribute__((ext_vector_type(8)));

__device__ float          Tg[(size_t)M_ROWS * 16];   // T = X@L1, fp32
__device__ unsigned short L1t[16 * K_DIM];           // L1^T, bf16
__device__ unsigned short L2t[N_OUT * 16];           // L2^T, bf16

__device__ __forceinline__ unsigned short f2bf(float f) {
    __bf16 h = (__bf16)f;                       // native v_cvt (RNE)
    union { __bf16 h; unsigned short u; } v; v.h = h;
    return v.u;
}

// ------------- merged prep: X->bf16 | W dequant+transpose | L1/L2 transpose
__global__ __launch_bounds__(256) void prep_kernel(
        const float* __restrict__ X,    ushort8v* __restrict__ Xh,
        const float* __restrict__ Wnf4, const float* __restrict__ c1p,
        const float* __restrict__ c2,   const float* __restrict__ L1,
        const float* __restrict__ L2,   unsigned short* __restrict__ Wt) {
    const int t = threadIdx.x;

    if (blockIdx.x < CVT_BLOCKS) {
        // ---- X fp32 -> bf16, 8 elems/thread
        size_t tid = (size_t)blockIdx.x * 256 + t;
        const float4* xp = (const float4*)X;
        float4 a = xp[tid * 2];
        float4 b = xp[tid * 2 + 1];
        ushort8v o;
        o[0] = f2bf(a.x); o[1] = f2bf(a.y); o[2] = f2bf(a.z); o[3] = f2bf(a.w);
        o[4] = f2bf(b.x); o[5] = f2bf(b.y); o[6] = f2bf(b.z); o[7] = f2bf(b.w);
        Xh[tid] = o;
        return;
    }

    if (blockIdx.x < CVT_BLOCKS + WP_BLOCKS) {
        // ---- W' = W_nf4 * c1 * c2, transposed store. Block: 64 n x 32 k.
        // Lane = n (coalesced column reads); each thread owns 8 contiguous k
        // for one n -> one 16B store into Wt[n][k].
        const int wb = blockIdx.x - CVT_BLOCKS;
        const int n  = (wb & 63) * 64 + (t & 63);
        const int k0 = (wb >> 6) * 32 + (t >> 6) * 8;
        const float c1 = *c1p;
        ushort8v o;
        #pragma unroll
        for (int kk = 0; kk < 8; ++kk) {
            size_t g = (size_t)(k0 + kk) * N_OUT + n;
            o[kk] = f2bf(Wnf4[g] * c1 * c2[g]);
        }
        *(ushort8v*)&Wt[(size_t)n * K_DIM + k0] = o;
        return;
    }

    // ---- tiny transposes: L1[K][16] -> L1t[16][K],  L2[16][N] -> L2t[N][16]
    const int idx = (blockIdx.x - CVT_BLOCKS - WP_BLOCKS) * 256 + t;
    if (idx < K_DIM) {                       // L1t, thread = one k
        const float4* lp = (const float4*)&L1[(size_t)idx * 16];
        float4 r0 = lp[0], r1 = lp[1], r2 = lp[2], r3 = lp[3];
        float v[16] = {r0.x, r0.y, r0.z, r0.w, r1.x, r1.y, r1.z, r1.w,
                       r2.x, r2.y, r2.z, r2.w, r3.x, r3.y, r3.z, r3.w};
        #pragma unroll
        for (int r = 0; r < 16; ++r)
            L1t[(size_t)r * K_DIM + idx] = f2bf(v[r]);
    } else {                                 // L2t, thread = one n
        const int n = idx - K_DIM;
        ushort8v a, b;
        #pragma unroll
        for (int r = 0; r < 8; ++r) a[r] = f2bf(L2[(size_t)r * N_OUT + n]);
        #pragma unroll
        for (int r = 0; r < 8; ++r) b[r] = f2bf(L2[(size_t)(r + 8) * N_OUT + n]);
        *(ushort8v*)&L2t[(size_t)n * 16]     = a;
        *(ushort8v*)&L2t[(size_t)n * 16 + 8] = b;
    }
}

// ------------------------------------------------- T = Xh @ L1  (8192 x 16)
// One wave per 16-row tile; full-K 16x16x32 MFMA chain. A-frag: lane reads
// Xh[m0+(l&15)][k + (l>>4)*8 ..+8]; B-frag: L1t[(l&15)][k + (l>>4)*8 ..+8].
// D layout: col=lane&15 (=r), row=(lane>>4)*4+reg (=m offset).
__global__ __launch_bounds__(64) void xl1_kernel(const __bf16* __restrict__ Xh) {
    const int m0   = blockIdx.x * 16;
    const int lane = threadIdx.x;
    const int l15  = lane & 15;
    const int l4   = lane >> 4;

    const __bf16* ap = Xh + (size_t)(m0 + l15) * K_DIM + l4 * 8;
    const __bf16* bp = (const __bf16*)L1t + (size_t)l15 * K_DIM + l4 * 8;

    f32x4 acc = {};
    #pragma unroll 8
    for (int k = 0; k < K_DIM; k += 32) {
        bf16x8 af = *(const bf16x8*)(ap + k);
        bf16x8 bf = *(const bf16x8*)(bp + k);
        acc = __builtin_amdgcn_mfma_f32_16x16x32_bf16(af, bf, acc, 0, 0, 0);
    }
    #pragma unroll
    for (int reg = 0; reg < 4; ++reg)
        Tg[(size_t)(m0 + l4 * 4 + reg) * 16 + l15] = acc[reg];
}

// ----------------------------------------------------------------- bf16 GEMM
// C[M][N] = A[M][K] * Bt[N][K]^T + T @ L2 ; 128x128 tile, BK=32, 4 waves.
// Wave w: 64x64 subtile as 2x2 grid of 32x32x16 MFMAs. (R3 verified structure;
// only addition is the K=16 LoRA MFMA step before the C-store.)
// LDS: row-major [row][32k], 4x16B slots/row, phys slot = logical ^ ((row>>1)&3).
__global__ __launch_bounds__(256) void gemm_bt_kernel(
        const __bf16* __restrict__ A, const __bf16* __restrict__ Bt,
        float* __restrict__ C) {
    __shared__ __bf16 As[128 * 32];   // 8 KB
    __shared__ __bf16 Bs[128 * 32];   // 8 KB

    const int t    = threadIdx.x;
    const int w    = t >> 6;
    const int lane = t & 63;
    const int half = lane >> 5;       // 0..1
    const int l32  = lane & 31;
    const int m0   = blockIdx.y * 128;
    const int n0   = blockIdx.x * 128;
    const int wm   = (w >> 1) * 64;
    const int wn   = (w & 1) * 64;

    // staging source permutation: lane l -> row l>>2,
    // phys slot l&3 holds logical slot (l&3)^((l>>3)&3)
    const int srow = lane >> 2;
    const int scol = ((lane & 3) ^ ((lane >> 3) & 3)) * 8;
    // read-side swizzle: (row>>1)&3 with row = base32 + l32
    const int rsw = (l32 >> 1) & 3;

    f32x16 acc[2][2] = {};

    for (int kb = 0; kb < K_DIM; kb += 32) {
        __syncthreads();
        #pragma unroll
        for (int j = 0; j < 2; ++j) {
            int row = w * 32 + j * 16 + srow;
            const __bf16* gp = A + (size_t)(m0 + row) * K_DIM + kb + scol;
            __builtin_amdgcn_global_load_lds(
                (const __attribute__((address_space(1))) unsigned int*)gp,
                (__attribute__((address_space(3))) unsigned int*)(As + (w * 32 + j * 16) * 32),
                16, 0, 0);
        }
        #pragma unroll
        for (int j = 0; j < 2; ++j) {
            int row = w * 32 + j * 16 + srow;
            const __bf16* gp = Bt + (size_t)(n0 + row) * K_DIM + kb + scol;
            __builtin_amdgcn_global_load_lds(
                (const __attribute__((address_space(1))) unsigned int*)gp,
                (__attribute__((address_space(3))) unsigned int*)(Bs + (w * 32 + j * 16) * 32),
                16, 0, 0);
        }
        __syncthreads();

        bf16x8 af[2][2], bf[2][2];
        #pragma unroll
        for (int mt = 0; mt < 2; ++mt)
            #pragma unroll
            for (int ks = 0; ks < 2; ++ks) {
                int row = wm + mt * 32 + l32;
                int slot = (2 * ks + half) ^ rsw;
                af[mt][ks] = *(const bf16x8*)(As + row * 32 + slot * 8);
            }
        #pragma unroll
        for (int nt = 0; nt < 2; ++nt)
            #pragma unroll
            for (int ks = 0; ks < 2; ++ks) {
                int row = wn + nt * 32 + l32;
                int slot = (2 * ks + half) ^ rsw;
                bf[nt][ks] = *(const bf16x8*)(Bs + row * 32 + slot * 8);
            }

        #pragma unroll
        for (int ks = 0; ks < 2; ++ks)
            #pragma unroll
            for (int mt = 0; mt < 2; ++mt)
                #pragma unroll
                for (int nt = 0; nt < 2; ++nt)
                    acc[mt][nt] = __builtin_amdgcn_mfma_f32_32x32x16_bf16(
                        af[mt][ks], bf[nt][ks], acc[mt][nt], 0, 0, 0);
    }

    // ---- LoRA epilogue: acc += T(128x16-slice) @ L2t^T via one K=16 MFMA.
    // 32x32x16 A-frag: lane row = l32, k = half*8 + j  -> T[row][half*8..+8]
    // 32x32x16 B-frag: lane col = l32, k = half*8 + j  -> L2t[col][half*8..+8]
    {
        bf16x8 afl[2], bfl[2];
        #pragma unroll
        for (int mt = 0; mt < 2; ++mt) {
            const float* tp = Tg + (size_t)(m0 + wm + mt * 32 + l32) * 16 + half * 8;
            float4 p0 = *(const float4*)tp;
            float4 p1 = *(const float4*)(tp + 4);
            afl[mt][0] = (__bf16)p0.x; afl[mt][1] = (__bf16)p0.y;
            afl[mt][2] = (__bf16)p0.z; afl[mt][3] = (__bf16)p0.w;
            afl[mt][4] = (__bf16)p1.x; afl[mt][5] = (__bf16)p1.y;
            afl[mt][6] = (__bf16)p1.z; afl[mt][7] = (__bf16)p1.w;
        }
        #pragma unroll
        for (int nt = 0; nt < 2; ++nt)
            bfl[nt] = *(const bf16x8*)((const __bf16*)L2t +
                        (size_t)(n0 + wn + nt * 32 + l32) * 16 + half * 8);
        #pragma unroll
        for (int mt = 0; mt < 2; ++mt)
            #pragma unroll
            for (int nt = 0; nt < 2; ++nt)
                acc[mt][nt] = __builtin_amdgcn_mfma_f32_32x32x16_bf16(
                    afl[mt], bfl[nt], acc[mt][nt], 0, 0, 0);
    }

    // epilogue: C/D 32x32 layout col=lane&31, row=(reg&3)+8*(reg>>2)+4*half
    #pragma unroll
    for (int mt = 0; mt < 2; ++mt)
        #pragma unroll
        for (int nt = 0; nt < 2; ++nt) {
            int col = n0 + wn + nt * 32 + l32;
            #pragma unroll
            for (int reg = 0; reg < 16; ++reg) {
                int row = m0 + wm + mt * 32 + (reg & 3) + 8 * (reg >> 2) + 4 * half;
                C[(size_t)row * N_OUT + col] = acc[mt][nt][reg];
            }
        }
}

extern "C" void kernel_launch(void* const* d_in, const int* in_sizes, int n_in,
                              void* d_out, int out_size, void* d_ws, size_t ws_size,
                              hipStream_t stream) {
    const float* X    = (const float*)d_in[0];
    const float* Wnf4 = (const float*)d_in[1];
    const float* c1   = (const float*)d_in[2];   // scalar
    const float* c2   = (const float*)d_in[3];
    const float* L1   = (const float*)d_in[4];
    const float* L2   = (const float*)d_in[5];
    float* Y = (float*)d_out;

    unsigned short* Xh = (unsigned short*)d_ws;                                       // 64 MB
    unsigned short* Wt = (unsigned short*)((char*)d_ws + (size_t)M_ROWS * K_DIM * 2); // 32 MB

    prep_kernel<<<CVT_BLOCKS + WP_BLOCKS + TR_BLOCKS, 256, 0, stream>>>(
        X, (ushort8v*)Xh, Wnf4, c1, c2, L1, L2, Wt);
    xl1_kernel<<<M_ROWS / 16, 64, 0, stream>>>((const __bf16*)Xh);
    gemm_bt_kernel<<<dim3(N_OUT / 128, M_ROWS / 128), 256, 0, stream>>>(
        (const __bf16*)Xh, (const __bf16*)Wt, Y);
}